// Round 12
// baseline (421.969 us; speedup 1.0000x reference)
//
#include <hip/hip_runtime.h>
#include <hip/hip_fp16.h>

#define K_DIM 4096
#define N_DIM 11008
#define NZ8   1376          // N_DIM/8
#define BM    256
#define BN    256
#define BK    64
#define NT_N  43            // N_DIM/BN
#define NKT   64            // K_DIM/BK
#define ATB   32768         // tile bytes = 256*64*2

typedef _Float16 f16x8 __attribute__((ext_vector_type(8)));
typedef float    f32x4 __attribute__((ext_vector_type(4)));

#define LGKM0() do { asm volatile("s_waitcnt lgkmcnt(0)" ::: "memory"); \
                     __builtin_amdgcn_sched_barrier(0); } while (0)
#define VMC0()  do { asm volatile("s_waitcnt vmcnt(0)"   ::: "memory"); \
                     __builtin_amdgcn_sched_barrier(0); } while (0)
#define BAR()   __builtin_amdgcn_s_barrier()

__device__ __forceinline__ f16x8 dq8(unsigned q, __half2 scp, __half2 nzp)
{
    const unsigned mu = 0xE400E400u;                 // (-1024,-1024) fp16
    const __half2 m1024 = *(const __half2*)&mu;
    union { __half2 h2[4]; f16x8 v; } p;
#pragma unroll
    for (int d = 0; d < 4; ++d) {
        unsigned t = ((q >> (4 * d)) & 0x000F000Fu) | 0x64006400u;
        p.h2[d] = __hfma2(__hadd2(*(const __half2*)&t, m1024), scp, nzp);  // sc*(w-z)
    }
    return p.v;
}

// ---- pre-pass: x f32 -> fp16 into ws, TILED + pre-swizzled + k-interleaved
// (identical to r11; GEMM A-stage is then linear global_load_lds + XOR read).
__global__ __launch_bounds__(256)
void r12_xcvt(const float* __restrict__ x, __half* __restrict__ xh, int nchunks)
{
    int c = blockIdx.x * 256 + threadIdx.x;
    const int stride = gridDim.x * 256;
    for (; c < nchunks; c += stride) {
        const int w    = c & 2047;
        const int tidx = c >> 11;
        const int row  = w >> 3;
        const int s    = w & 7;
        const int ls   = s ^ (row & 7);
        const int mt   = tidx >> 6;
        const int kt   = tidx & 63;
        const size_t gm = (size_t)mt * 256 + row;
        const int kb   = kt * 64 + ls * 8;
        const float4 f0 = *(const float4*)(x + gm * K_DIM + kb);
        const float4 f1 = *(const float4*)(x + gm * K_DIM + kb + 4);
        union { __half2 h2[4]; int4 v; } p;
        p.h2[0] = __floats2half2_rn(f0.x, f1.x);
        p.h2[1] = __floats2half2_rn(f0.y, f1.y);
        p.h2[2] = __floats2half2_rn(f0.z, f1.z);
        p.h2[3] = __floats2half2_rn(f0.w, f1.w);
        ((int4*)xh)[c] = p.v;
    }
}

// APATH1 fallback: inline f32->fp16 convert + swizzled ds_write (no ws).
__device__ __forceinline__ void stage_a_cvt(const float* __restrict__ x,
                                            unsigned char* __restrict__ abuf,
                                            int bm0, int kt, int arow, int ahalf, int asw)
{
    const float* src = x + (size_t)(bm0 + arow) * K_DIM + kt * 64 + ahalf * 32;
    unsigned char* aw = abuf + arow * 128;
#pragma unroll
    for (int c = 0; c < 4; ++c) {
        const float4 f0 = *(const float4*)(src + c * 8);
        const float4 f1 = *(const float4*)(src + c * 8 + 4);
        union { __half2 h2[4]; f16x8 v; } p;
        p.h2[0] = __floats2half2_rn(f0.x, f1.x);
        p.h2[1] = __floats2half2_rn(f0.y, f1.y);
        p.h2[2] = __floats2half2_rn(f0.z, f1.z);
        p.h2[3] = __floats2half2_rn(f0.w, f1.w);
        *(f16x8*)(aw + ((((ahalf * 4 + c) << 4) ^ asw))) = p.v;
    }
}

// ---- fused GEMM, 8-phase-style schedule (4 phases per K-tile, dbuf LDS).
// Dataflow identical to r11; only the k-loop schedule changed (T3+T4+T5).
template<int APATH>
__global__ __launch_bounds__(512, 2)
void r12_gemm(const float* __restrict__ x,
              const __half* __restrict__ xh,
              const int*   __restrict__ qweight,
              const int*   __restrict__ qzeros,
              const float* __restrict__ scales,
              const float* __restrict__ bias,
              float* __restrict__ out)
{
    __shared__ __align__(16) unsigned char Asm[2][ATB];   // 64 KB
    __shared__ __align__(16) unsigned char Bsm[2][ATB];   // 64 KB

    const int tid  = threadIdx.x;
    const int lane = tid & 63;
    const int wid  = tid >> 6;
    const int wr   = (wid >> 2) * 128;   // wave M offset (0,128)
    const int wc   = (wid & 3) * 64;     // wave N offset (0,64,128,192)

    int bid = blockIdx.x;                // XCD swizzle (688 = 8*86)
    const int cpx = gridDim.x >> 3;
    bid = (bid & 7) * cpx + (bid >> 3);
    const int bm0 = (bid / NT_N) * BM;
    const int bn0 = (bid % NT_N) * BN;

    // B staging: col bnn, rows {bq, bq+2, bq+4, bq+6} per k-tile
    const int bnn = tid & 255;
    const int bq  = tid >> 8;            // 0..1
    const int ngl = bn0 + bnn;
    const int* qwp = qwp = qweight + (size_t)bq * N_DIM + ngl;
    const int bsw = bnn & 7;

    // A staging (APATH0): tiled pre-swizzled xh, linear global_load_lds
    const char* agp = (const char*)xh + ((size_t)(bm0 >> 8) * NKT) * ATB + tid * 16;
    // A staging (APATH1)
    const int arow = tid >> 1, ahalf = tid & 1;
    const int asw  = (arow & 7) << 4;

    // fragment addressing
    const int frow = lane & 15, kb8 = lane >> 4, fsw = frow & 7;
    const int aBase = (wr + frow) * 128;
    const int bBase = (wc + frow) * 128;
    const int so0 = ((kb8 ^ fsw) << 4);          // kh = 0
    const int so1 = (((4 + kb8) ^ fsw) << 4);    // kh = 1

    f32x4 acc[8][4];
#pragma unroll
    for (int m = 0; m < 8; ++m)
#pragma unroll
        for (int n = 0; n < 4; ++n)
            acc[m][n] = (f32x4){0.f, 0.f, 0.f, 0.f};

    __half2 scp, nzp;
    {   // group-0 dequant scalars
        const float sc = scales[ngl];
        const unsigned zq = (unsigned)qzeros[ngl >> 3];
        const float zf = (float)((zq >> ((ngl & 7) * 4)) & 15u);
        const __half sh = __float2half_rn(sc), nh = __float2half_rn(-sc * zf);
        scp = __half2(sh, sh); nzp = __half2(nh, nh);
    }

    // ---- prologue: stage tile 0 into buffer 0
    if constexpr (APATH == 0) {
#pragma unroll
        for (int i = 0; i < 4; ++i)
            __builtin_amdgcn_global_load_lds((const unsigned int*)(agp + i * 8192),
                                             (unsigned int*)&Asm[0][tid * 16 + i * 8192],
                                             16, 0, 0);
    } else {
        stage_a_cvt(x, &Asm[0][0], bm0, 0, arow, ahalf, asw);
    }
    {
        unsigned q[4];
#pragma unroll
        for (int i = 0; i < 4; ++i) q[i] = (unsigned)qwp[(size_t)(2 * i) * N_DIM];
#pragma unroll
        for (int i = 0; i < 4; ++i)
            *(f16x8*)(&Bsm[0][bnn * 128 + (((bq + 2 * i) ^ bsw) << 4)]) = dq8(q[i], scp, nzp);
    }
    __syncthreads();

    float    nsc = 0.f;
    unsigned nzq = 0u;

    for (int kt = 0; kt < NKT; ++kt) {
        const int cur = kt & 1, nxt = cur ^ 1;
        const bool hn = (kt + 1 < NKT);
        unsigned qn0 = 0, qn1 = 0, qn2 = 0, qn3 = 0;
        const unsigned char* Ac = &Asm[cur][0];
        const unsigned char* Bc = &Bsm[cur][0];
        f16x8 a0, a1, a2, a3, b0, b1, b2, b3;

        // ===== PHASE 0: ds_read (mh0,kh0)+B(kh0); stage-issue for t+1 =====
        a0 = *(const f16x8*)(Ac + aBase + 0 * 2048 + so0);
        a1 = *(const f16x8*)(Ac + aBase + 1 * 2048 + so0);
        a2 = *(const f16x8*)(Ac + aBase + 2 * 2048 + so0);
        a3 = *(const f16x8*)(Ac + aBase + 3 * 2048 + so0);
        b0 = *(const f16x8*)(Bc + bBase + 0 * 2048 + so0);
        b1 = *(const f16x8*)(Bc + bBase + 1 * 2048 + so0);
        b2 = *(const f16x8*)(Bc + bBase + 2 * 2048 + so0);
        b3 = *(const f16x8*)(Bc + bBase + 3 * 2048 + so0);
        if (hn) {
            if constexpr (APATH == 0) {
                const char* ag = agp + (size_t)(kt + 1) * ATB;
#pragma unroll
                for (int i = 0; i < 4; ++i)
                    __builtin_amdgcn_global_load_lds((const unsigned int*)(ag + i * 8192),
                                                     (unsigned int*)&Asm[nxt][tid * 16 + i * 8192],
                                                     16, 0, 0);
            }
            qn0 = (unsigned)qwp[(size_t)((kt + 1) * 8 + 0) * N_DIM];
            qn1 = (unsigned)qwp[(size_t)((kt + 1) * 8 + 2) * N_DIM];
            qn2 = (unsigned)qwp[(size_t)((kt + 1) * 8 + 4) * N_DIM];
            qn3 = (unsigned)qwp[(size_t)((kt + 1) * 8 + 6) * N_DIM];
            if (((kt + 1) & 1) == 0) {           // next tile starts a new group
                const int g = (kt + 1) >> 1;
                nsc = scales[(size_t)g * N_DIM + ngl];
                nzq = (unsigned)qzeros[(size_t)g * NZ8 + (ngl >> 3)];
            }
        }
        BAR(); LGKM0();
        __builtin_amdgcn_s_setprio(1);
#pragma unroll
        for (int n = 0; n < 4; ++n) {
            const f16x8 bb = (n == 0) ? b0 : (n == 1) ? b1 : (n == 2) ? b2 : b3;
            acc[0][n] = __builtin_amdgcn_mfma_f32_16x16x32_f16(a0, bb, acc[0][n], 0, 0, 0);
            acc[1][n] = __builtin_amdgcn_mfma_f32_16x16x32_f16(a1, bb, acc[1][n], 0, 0, 0);
            acc[2][n] = __builtin_amdgcn_mfma_f32_16x16x32_f16(a2, bb, acc[2][n], 0, 0, 0);
            acc[3][n] = __builtin_amdgcn_mfma_f32_16x16x32_f16(a3, bb, acc[3][n], 0, 0, 0);
        }
        __builtin_amdgcn_s_setprio(0);
        BAR();

        // ===== PHASE 1: ds_read (mh1,kh0); MFMA with held B(kh0) =====
        a0 = *(const f16x8*)(Ac + aBase + 8192 + 0 * 2048 + so0);
        a1 = *(const f16x8*)(Ac + aBase + 8192 + 1 * 2048 + so0);
        a2 = *(const f16x8*)(Ac + aBase + 8192 + 2 * 2048 + so0);
        a3 = *(const f16x8*)(Ac + aBase + 8192 + 3 * 2048 + so0);
        BAR(); LGKM0();
        __builtin_amdgcn_s_setprio(1);
#pragma unroll
        for (int n = 0; n < 4; ++n) {
            const f16x8 bb = (n == 0) ? b0 : (n == 1) ? b1 : (n == 2) ? b2 : b3;
            acc[4][n] = __builtin_amdgcn_mfma_f32_16x16x32_f16(a0, bb, acc[4][n], 0, 0, 0);
            acc[5][n] = __builtin_amdgcn_mfma_f32_16x16x32_f16(a1, bb, acc[5][n], 0, 0, 0);
            acc[6][n] = __builtin_amdgcn_mfma_f32_16x16x32_f16(a2, bb, acc[6][n], 0, 0, 0);
            acc[7][n] = __builtin_amdgcn_mfma_f32_16x16x32_f16(a3, bb, acc[7][n], 0, 0, 0);
        }
        __builtin_amdgcn_s_setprio(0);
        BAR();

        // ===== PHASE 2: ds_read (mh0,kh1)+B(kh1) =====
        a0 = *(const f16x8*)(Ac + aBase + 0 * 2048 + so1);
        a1 = *(const f16x8*)(Ac + aBase + 1 * 2048 + so1);
        a2 = *(const f16x8*)(Ac + aBase + 2 * 2048 + so1);
        a3 = *(const f16x8*)(Ac + aBase + 3 * 2048 + so1);
        b0 = *(const f16x8*)(Bc + bBase + 0 * 2048 + so1);
        b1 = *(const f16x8*)(Bc + bBase + 1 * 2048 + so1);
        b2 = *(const f16x8*)(Bc + bBase + 2 * 2048 + so1);
        b3 = *(const f16x8*)(Bc + bBase + 3 * 2048 + so1);
        BAR(); LGKM0();
        __builtin_amdgcn_s_setprio(1);
#pragma unroll
        for (int n = 0; n < 4; ++n) {
            const f16x8 bb = (n == 0) ? b0 : (n == 1) ? b1 : (n == 2) ? b2 : b3;
            acc[0][n] = __builtin_amdgcn_mfma_f32_16x16x32_f16(a0, bb, acc[0][n], 0, 0, 0);
            acc[1][n] = __builtin_amdgcn_mfma_f32_16x16x32_f16(a1, bb, acc[1][n], 0, 0, 0);
            acc[2][n] = __builtin_amdgcn_mfma_f32_16x16x32_f16(a2, bb, acc[2][n], 0, 0, 0);
            acc[3][n] = __builtin_amdgcn_mfma_f32_16x16x32_f16(a3, bb, acc[3][n], 0, 0, 0);
        }
        __builtin_amdgcn_s_setprio(0);
        BAR();

        // ===== PHASE 3: ds_read (mh1,kh1); dequant+ds_write for t+1 =====
        a0 = *(const f16x8*)(Ac + aBase + 8192 + 0 * 2048 + so1);
        a1 = *(const f16x8*)(Ac + aBase + 8192 + 1 * 2048 + so1);
        a2 = *(const f16x8*)(Ac + aBase + 8192 + 2 * 2048 + so1);
        a3 = *(const f16x8*)(Ac + aBase + 8192 + 3 * 2048 + so1);
        if (hn) {
            if (((kt + 1) & 1) == 0) {
                const float zf = (float)((nzq >> ((ngl & 7) * 4)) & 15u);
                const __half sh = __float2half_rn(nsc), nh = __float2half_rn(-nsc * zf);
                scp = __half2(sh, sh); nzp = __half2(nh, nh);
            }
            unsigned char* bw = &Bsm[nxt][bnn * 128];
            *(f16x8*)(bw + (((bq + 0) ^ bsw) << 4)) = dq8(qn0, scp, nzp);
            *(f16x8*)(bw + (((bq + 2) ^ bsw) << 4)) = dq8(qn1, scp, nzp);
            *(f16x8*)(bw + (((bq + 4) ^ bsw) << 4)) = dq8(qn2, scp, nzp);
            *(f16x8*)(bw + (((bq + 6) ^ bsw) << 4)) = dq8(qn3, scp, nzp);
            if constexpr (APATH == 1)
                stage_a_cvt(x, &Asm[nxt][0], bm0, kt + 1, arow, ahalf, asw);
        }
        BAR(); LGKM0();
        __builtin_amdgcn_s_setprio(1);
#pragma unroll
        for (int n = 0; n < 4; ++n) {
            const f16x8 bb = (n == 0) ? b0 : (n == 1) ? b1 : (n == 2) ? b2 : b3;
            acc[4][n] = __builtin_amdgcn_mfma_f32_16x16x32_f16(a0, bb, acc[4][n], 0, 0, 0);
            acc[5][n] = __builtin_amdgcn_mfma_f32_16x16x32_f16(a1, bb, acc[5][n], 0, 0, 0);
            acc[6][n] = __builtin_amdgcn_mfma_f32_16x16x32_f16(a2, bb, acc[6][n], 0, 0, 0);
            acc[7][n] = __builtin_amdgcn_mfma_f32_16x16x32_f16(a3, bb, acc[7][n], 0, 0, 0);
        }
        __builtin_amdgcn_s_setprio(0);
        VMC0();               // A-lds for t+1 provably old -> ~free drain
        __syncthreads();      // tile boundary (full fence, buffer swap)
    }

    // ---- epilogue: C row=(lane>>4)*4+j, col=lane&15 (m89 layout)
    const int crow0 = (lane >> 4) << 2, ccol = lane & 15;
#pragma unroll
    for (int n = 0; n < 4; ++n) {
        const int col = bn0 + wc + n * 16 + ccol;
        const float bv = bias[col];
#pragma unroll
        for (int m = 0; m < 8; ++m) {
            const int row = bm0 + wr + m * 16 + crow0;
#pragma unroll
            for (int j = 0; j < 4; ++j)
                out[(size_t)(row + j) * N_DIM + col] = acc[m][n][j] + bv;
        }
    }
}

extern "C" void kernel_launch(void* const* d_in, const int* in_sizes, int n_in,
                              void* d_out, int out_size, void* d_ws, size_t ws_size,
                              hipStream_t stream)
{
    const float* x   = (const float*)d_in[0];
    const int*   qw  = (const int*)d_in[1];
    const int*   qz  = (const int*)d_in[2];
    const float* scl = (const float*)d_in[3];
    const float* bs  = (const float*)d_in[4];
    float* out = (float*)d_out;

    const int M = in_sizes[0] / K_DIM;               // 4096
    const size_t xh_bytes = (size_t)M * K_DIM * 2;   // 33.6 MB
    dim3 grid((M / BM) * NT_N);                      // 16*43 = 688

    if (ws_size >= xh_bytes) {
        __half* xh = (__half*)d_ws;
        const int nchunks = M * K_DIM / 8;
        hipLaunchKernelGGL(r12_xcvt, dim3(2048), dim3(256), 0, stream, x, xh, nchunks);
        hipLaunchKernelGGL((r12_gemm<0>), grid, dim3(512), 0, stream,
                           x, xh, qw, qz, scl, bs, out);
    } else {
        hipLaunchKernelGGL((r12_gemm<1>), grid, dim3(512), 0, stream,
                           x, (const __half*)nullptr, qw, qz, scl, bs, out);
    }
}

// Round 13
// 387.385 us; speedup vs baseline: 1.0893x; 1.0893x over previous
//
#include <hip/hip_runtime.h>
#include <hip/hip_fp16.h>

#define K_DIM 4096
#define N_DIM 11008
#define NZ8   1376          // N_DIM/8
#define BM    256
#define BN    256
#define NT_N  43            // N_DIM/BN
#define NKT   64            // K_DIM/64
#define ATB   32768         // tile bytes = 256*64*2

typedef _Float16 f16x8 __attribute__((ext_vector_type(8)));
typedef float    f32x4 __attribute__((ext_vector_type(4)));

// ---------------- waits / fences ----------------
#define SB()    __builtin_amdgcn_sched_barrier(0)
#define BAR()   __builtin_amdgcn_s_barrier()
#define VMW(N)  do { asm volatile("s_waitcnt vmcnt(" #N ")" ::: "memory"); SB(); } while (0)
#define LGKM0() do { asm volatile("s_waitcnt lgkmcnt(0)" ::: "memory"); SB(); } while (0)

// ---------------- dequant: 1 int32 -> 8 fp16 (k,k+4 interleave) ------------
__device__ __forceinline__ f16x8 dq8(unsigned q, __half2 scp, __half2 nzp)
{
    const unsigned mu = 0xE400E400u;                 // (-1024,-1024) fp16
    const __half2 m1024 = *(const __half2*)&mu;
    union { __half2 h2[4]; f16x8 v; } p;
#pragma unroll
    for (int d = 0; d < 4; ++d) {
        unsigned t = ((q >> (4 * d)) & 0x000F000Fu) | 0x64006400u;
        p.h2[d] = __hfma2(__hadd2(*(const __half2*)&t, m1024), scp, nzp);  // sc*(w-z)
    }
    return p.v;
}

__device__ __forceinline__ void mk_scp(unsigned su, unsigned zu, int ngl,
                                       __half2& scp, __half2& nzp)
{
    const float sc = __uint_as_float(su);
    const float zf = (float)((zu >> ((ngl & 7) * 4)) & 15u);
    const __half sh = __float2half_rn(sc), nh = __float2half_rn(-sc * zf);
    scp = __half2(sh, sh); nzp = __half2(nh, nh);
}

// ---- pre-pass: x f32 -> fp16 ws, layout [mtile][ktile][kh][slot][row][16B],
// 16B chunk = 8 f16 of k = kt*64+kh*32+sl*8 in order (k0,k4,k1,k5,k2,k6,k3,k7).
// GEMM then stages halves with linear global_load_lds; all LDS reads are
// wave-contiguous (zero bank conflicts, no swizzle).
__global__ __launch_bounds__(256)
void r13_xcvt(const float* __restrict__ x, __half* __restrict__ xh, int nchunks)
{
    int c = blockIdx.x * 256 + threadIdx.x;
    const int stride = gridDim.x * 256;
    for (; c < nchunks; c += stride) {
        const int row = c & 255;
        const int sl  = (c >> 8) & 3;
        const int kh  = (c >> 10) & 1;
        const int tl  = c >> 11;
        const int mt  = tl >> 6;
        const int kt  = tl & 63;
        const size_t gm = (size_t)mt * 256 + row;
        const int kb = kt * 64 + kh * 32 + sl * 8;
        const float4 f0 = *(const float4*)(x + gm * K_DIM + kb);
        const float4 f1 = *(const float4*)(x + gm * K_DIM + kb + 4);
        union { __half2 h2[4]; int4 v; } p;
        p.h2[0] = __floats2half2_rn(f0.x, f1.x);
        p.h2[1] = __floats2half2_rn(f0.y, f1.y);
        p.h2[2] = __floats2half2_rn(f0.z, f1.z);
        p.h2[3] = __floats2half2_rn(f0.w, f1.w);
        ((int4*)xh)[c] = p.v;
    }
}

// ---------------- ledger issue helpers ----------------
#define ISSUE_Q(D0, D1, T, H) do { \
    const int* _a0 = qwp + (size_t)((T) * 8 + 4 * (H)) * N_DIM; \
    const int* _a1 = qwp + (size_t)((T) * 8 + 4 * (H) + 2) * N_DIM; \
    asm volatile("global_load_dword %0, %2, off\n\t" \
                 "global_load_dword %1, %3, off" \
                 : "=&v"(D0), "=&v"(D1) : "v"(_a0), "v"(_a1) : "memory"); \
} while (0)

#define ISSUE_S(DS, DZ, G) do { \
    const float* _sa = scales + (size_t)(G) * N_DIM + ngl; \
    const int*   _za = qzeros + (size_t)(G) * NZ8 + (ngl >> 3); \
    asm volatile("global_load_dword %0, %2, off\n\t" \
                 "global_load_dword %1, %3, off" \
                 : "=&v"(DS), "=&v"(DZ) : "v"(_sa), "v"(_za) : "memory"); \
} while (0)

#define ISSUE_A(BUFP, T, H) do { \
    const char* _s = agp + (size_t)(T) * ATB + (H) * 16384; \
    __builtin_amdgcn_global_load_lds((const unsigned int*)_s, \
        (unsigned int*)((BUFP) + (H) * 16384 + tid * 16), 16, 0, 0); \
    __builtin_amdgcn_global_load_lds((const unsigned int*)(_s + 8192), \
        (unsigned int*)((BUFP) + (H) * 16384 + tid * 16 + 8192), 16, 0, 0); \
} while (0)

#define FRAGS(ARp, BRp, KH) do { \
    _Pragma("unroll") for (int m = 0; m < 8; ++m) \
        af[m] = *(const f16x8*)((ARp) + (KH) * 16384 + aOff + m * 256); \
    _Pragma("unroll") for (int n = 0; n < 4; ++n) \
        bf[n] = *(const f16x8*)((BRp) + (KH) * 16384 + bOff + n * 256); \
} while (0)

#define MFMA32() do { \
    __builtin_amdgcn_s_setprio(1); \
    _Pragma("unroll") for (int m = 0; m < 8; ++m) \
        _Pragma("unroll") for (int n = 0; n < 4; ++n) \
            acc[m][n] = __builtin_amdgcn_mfma_f32_16x16x32_f16(af[m], bf[n], acc[m][n], 0, 0, 0); \
    __builtin_amdgcn_s_setprio(0); \
    SB(); \
} while (0)

#define DQ2(BWp, H, Q0, Q1) do { \
    *(f16x8*)((BWp) + (H) * 16384 + bq * 4096 + bnn * 16)       = dq8(Q0, scp, nzp); \
    *(f16x8*)((BWp) + (H) * 16384 + (bq + 2) * 4096 + bnn * 16) = dq8(Q1, scp, nzp); \
} while (0)

// ---- fused GEMM: 256x256, BK=64, 8 waves, counted-vmcnt pipeline (T3+T4+T5).
// A: global_load_lds from pre-cvt ws, staged per k-half with 3-phase latency
// cover into the k-half freed one phase earlier. B: reg-dequant with 2-phase
// q cover. vmcnt never drains to 0 in the steady loop.
__global__ __launch_bounds__(512, 2)
void r13_gemm(const __half* __restrict__ xh,
              const int*   __restrict__ qweight,
              const int*   __restrict__ qzeros,
              const float* __restrict__ scales,
              const float* __restrict__ bias,
              float* __restrict__ out)
{
    __shared__ __align__(16) unsigned char A0s[ATB], A1s[ATB];   // 64 KB
    __shared__ __align__(16) unsigned char B0s[ATB], B1s[ATB];   // 64 KB

    const int tid  = threadIdx.x;
    const int lane = tid & 63;
    const int wid  = tid >> 6;
    const int wr   = (wid >> 2) * 128;
    const int wc   = (wid & 3) * 64;

    int bid = blockIdx.x;                 // XCD swizzle (688 = 8*86)
    const int cpx = gridDim.x >> 3;
    bid = (bid & 7) * cpx + (bid >> 3);
    const int bm0 = (bid / NT_N) * BM;
    const int bn0 = (bid % NT_N) * BN;

    const int bnn = tid & 255;
    const int bq  = tid >> 8;             // 0..1
    const int ngl = bn0 + bnn;
    const int* qwp = qweight + (size_t)bq * N_DIM + ngl;
    const char* agp = (const char*)xh + ((size_t)(bm0 >> 8) * NKT) * ATB + tid * 16;

    const int frow = lane & 15, kb8 = lane >> 4;
    const int aOff = kb8 * 4096 + (wr + frow) * 16;
    const int bOff = kb8 * 4096 + (wc + frow) * 16;

    unsigned char *aR = A0s, *aW = A1s, *bR = B0s, *bW = B1s;

    f32x4 acc[8][4];
#pragma unroll
    for (int m = 0; m < 8; ++m)
#pragma unroll
        for (int n = 0; n < 4; ++n)
            acc[m][n] = (f32x4){0.f, 0.f, 0.f, 0.f};
    f16x8 af[8], bf[4];
    __half2 scp, nzp;
    unsigned qc0, qc1, qc2, qc3, qn0, qn1, qn2, qn3;
    unsigned sSc2, sZq2;

    // ---- prologue: S0/S1 plain-loaded & retired before the ledger begins
    unsigned sSc0 = __float_as_uint(scales[ngl]);
    unsigned sZq0 = (unsigned)qzeros[ngl >> 3];
    unsigned sSc1 = __float_as_uint(scales[(size_t)N_DIM + ngl]);
    unsigned sZq1 = (unsigned)qzeros[NZ8 + (ngl >> 3)];
    asm volatile("" : "+v"(sSc0), "+v"(sZq0), "+v"(sSc1), "+v"(sZq1));
    VMW(0);
    // ledger: [q0h0, q0h1, A(0,h0)] + entering set [q1h0, A(0,h1), q1h1, A(1,h0)]
    unsigned q00, q01, q02, q03;
    ISSUE_Q(q00, q01, 0, 0);
    ISSUE_Q(q02, q03, 0, 1);
    ISSUE_A(aR, 0, 0); SB();
    ISSUE_Q(qc0, qc1, 1, 0);
    ISSUE_A(aR, 0, 1);
    ISSUE_Q(qc2, qc3, 1, 1);
    ISSUE_A(aW, 1, 0); SB();
    VMW(10);                               // q[0] done
    mk_scp(sSc0, sZq0, ngl, scp, nzp);
    DQ2(bR, 0, q00, q01);
    DQ2(bR, 1, q02, q03);
    LGKM0(); VMW(8);                       // A(0,h0) done; 8 ledger loads remain
    BAR();

    // ---- main loop: super-iter u = tiles (2u, 2u+1); issues for 2u+2, 2u+3
    for (int u = 0; u < 31; ++u) {
        const int t0 = 2 * u;
        mk_scp(sSc0, sZq0, ngl, scp, nzp);           // group u (for B[2u+1])
        // P1 = (2u, h0)
        FRAGS(aR, bR, 0); SB();
        ISSUE_Q(qn0, qn1, t0 + 2, 0);
        ISSUE_A(aW, t0 + 1, 1); SB();
        VMW(10);                                      // q[2u+1][h0] arrived
        DQ2(bW, 0, qc0, qc1);
        LGKM0(); VMW(8);                              // A(2u,h1) arrived
        BAR();
        MFMA32();
        // P2 = (2u, h1)
        FRAGS(aR, bR, 1); SB();
        ISSUE_Q(qn2, qn3, t0 + 2, 1);
        ISSUE_A(aR, t0 + 2, 0);                       // into freed h0 of cur buf
        { const int gS = (u + 2 <= 31) ? (u + 2) : 31; ISSUE_S(sSc2, sZq2, gS); }
        SB();
        VMW(12);                                      // q[2u+1][h1]
        DQ2(bW, 1, qc2, qc3);
        LGKM0(); VMW(10);                             // A(2u+1,h0)
        BAR();
        MFMA32();
        { unsigned char* tp = aR; aR = aW; aW = tp; }
        { unsigned char* tp = bR; bR = bW; bW = tp; }
        qc0 = qn0; qc1 = qn1; qc2 = qn2; qc3 = qn3;
        mk_scp(sSc1, sZq1, ngl, scp, nzp);           // group u+1 (for B[2u+2])
        // P3 = (2u+1, h0)
        FRAGS(aR, bR, 0); SB();
        ISSUE_Q(qn0, qn1, t0 + 3, 0);
        ISSUE_A(aW, t0 + 2, 1); SB();
        VMW(12);                                      // q[2u+2][h0]
        DQ2(bW, 0, qc0, qc1);
        LGKM0(); VMW(10);                             // A(2u+1,h1)
        BAR();
        MFMA32();
        // P4 = (2u+1, h1)
        FRAGS(aR, bR, 1); SB();
        ISSUE_Q(qn2, qn3, t0 + 3, 1);
        ISSUE_A(aR, t0 + 3, 0); SB();
        VMW(12);                                      // q[2u+2][h1]
        DQ2(bW, 1, qc2, qc3);
        LGKM0(); VMW(10);                             // A(2u+2,h0)
        BAR();
        MFMA32();
        { unsigned char* tp = aR; aR = aW; aW = tp; }
        { unsigned char* tp = bR; bR = bW; bW = tp; }
        qc0 = qn0; qc1 = qn1; qc2 = qn2; qc3 = qn3;
        sSc0 = sSc1; sZq0 = sZq1; sSc1 = sSc2; sZq1 = sZq2;
    }

    // ---- tail: tiles 62, 63 (group 31 = sSc0 after rotations)
    mk_scp(sSc0, sZq0, ngl, scp, nzp);
    // (62, h0)
    FRAGS(aR, bR, 0); SB();
    ISSUE_A(aW, 63, 1); SB();                         // A(63,h1)
    VMW(8);                                           // q[63][h0]
    DQ2(bW, 0, qc0, qc1);
    LGKM0(); VMW(6);                                  // A(62,h1)
    BAR();
    MFMA32();
    // (62, h1)
    FRAGS(aR, bR, 1); SB();
    VMW(4);                                           // q[63][h1]
    DQ2(bW, 1, qc2, qc3);
    LGKM0(); VMW(2);                                  // A(63,h0)
    BAR();
    MFMA32();
    { unsigned char* tp = aR; aR = aW; aW = tp; }
    { unsigned char* tp = bR; bR = bW; bW = tp; }
    // (63, h0)
    FRAGS(aR, bR, 0);
    MFMA32();
    VMW(0);                                           // A(63,h1) DMA done
    BAR();
    // (63, h1)
    FRAGS(aR, bR, 1);
    MFMA32();

    // ---- epilogue: C row=(lane>>4)*4+j, col=lane&15 (m89 layout)
    const int crow0 = (lane >> 4) << 2, ccol = lane & 15;
#pragma unroll
    for (int n = 0; n < 4; ++n) {
        const int col = bn0 + wc + n * 16 + ccol;
        const float bv = bias[col];
#pragma unroll
        for (int m = 0; m < 8; ++m) {
            const int row = bm0 + wr + m * 16 + crow0;
#pragma unroll
            for (int j = 0; j < 4; ++j)
                out[(size_t)(row + j) * N_DIM + col] = acc[m][n][j] + bv;
        }
    }
}

// ---------------- fallback (ws too small): proven r8 kernel ----------------
typedef __bf16 bf16x8 __attribute__((ext_vector_type(8)));

__global__ __launch_bounds__(256, 2)
void r13_fb(const float* __restrict__ x,
            const int*   __restrict__ qweight,
            const int*   __restrict__ qzeros,
            const float* __restrict__ scales,
            const float* __restrict__ bias,
            float* __restrict__ out)
{
    __shared__ __align__(16) unsigned char Asm[128 * 64 * 2];
    __shared__ __align__(16) unsigned char Bsm[128 * 64 * 2];
    const int tid = threadIdx.x, lane = tid & 63, wv = tid >> 6;
    const int wr = (wv >> 1) * 64, wc = (wv & 1) * 64;
    int bid = blockIdx.x;
    const int cpx = gridDim.x >> 3;
    bid = (bid & 7) * cpx + (bid >> 3);
    const int bm0 = (bid / 86) * 128, bn0 = (bid % 86) * 128;
    const int ar = tid >> 4, ac4 = tid & 15;
    const float* xp = x + (size_t)(bm0 + ar) * K_DIM + ac4 * 4;
    unsigned char* aw = Asm + ar * 128 + ((ac4 * 8) ^ ((ar & 7) << 4));
    const int bnn = tid & 127, bk8q = tid >> 7, ngl = bn0 + bnn;
    const int* qwp = qweight + (size_t)bk8q * N_DIM + ngl;
    unsigned char* bw = Bsm + bnn * 128;
    const int bsw = bnn & 7;
    const int frow = lane & 15, kb8 = lane >> 4, fsw = frow & 7;
    f32x4 acc[4][4];
#pragma unroll
    for (int m = 0; m < 4; ++m)
#pragma unroll
        for (int n = 0; n < 4; ++n) acc[m][n] = (f32x4){0.f, 0.f, 0.f, 0.f};
    float sc = 0.f, nsz = 0.f;
    for (int kt = 0; kt < K_DIM / 64; ++kt) {
        const int k0 = kt * 64;
        if ((k0 & 127) == 0) {
            const int g = k0 >> 7;
            sc = scales[(size_t)g * N_DIM + ngl];
            const unsigned zq = (unsigned)qzeros[(size_t)g * NZ8 + (ngl >> 3)];
            nsz = -sc * (float)((zq >> ((ngl & 7) * 4)) & 15u);
        }
#pragma unroll
        for (int i = 0; i < 8; ++i) {
            const float4 v = *(const float4*)(xp + (size_t)i * 16 * K_DIM + k0);
            union { __bf16 h[4]; unsigned long long u; } p;
            p.h[0] = (__bf16)v.x; p.h[1] = (__bf16)v.y;
            p.h[2] = (__bf16)v.z; p.h[3] = (__bf16)v.w;
            *(unsigned long long*)(aw + i * 16 * 128) = p.u;
        }
#pragma unroll
        for (int i = 0; i < 4; ++i) {
            const int k8 = 2 * i + bk8q;
            const unsigned q = (unsigned)qwp[(size_t)(kt * 8 + 2 * i) * N_DIM];
            union { __bf16 h[8]; bf16x8 v8; } p;
#pragma unroll
            for (int j = 0; j < 8; ++j)
                p.h[j] = (__bf16)__builtin_fmaf(sc, (float)((q >> (4 * j)) & 15u), nsz);
            *(bf16x8*)(bw + ((k8 ^ bsw) << 4)) = p.v8;
        }
        __syncthreads();
#pragma unroll
        for (int kh = 0; kh < 2; ++kh) {
            const int ksl = (kh << 2) + kb8;
            bf16x8 a2[4], b2[4];
#pragma unroll
            for (int m = 0; m < 4; ++m)
                a2[m] = *(const bf16x8*)(Asm + (wr + m * 16 + frow) * 128 + ((ksl ^ fsw) << 4));
#pragma unroll
            for (int n = 0; n < 4; ++n)
                b2[n] = *(const bf16x8*)(Bsm + (wc + n * 16 + frow) * 128 + ((ksl ^ fsw) << 4));
#pragma unroll
            for (int m = 0; m < 4; ++m)
#pragma unroll
                for (int n = 0; n < 4; ++n)
                    acc[m][n] = __builtin_amdgcn_mfma_f32_16x16x32_bf16(a2[m], b2[n], acc[m][n], 0, 0, 0);
        }
        __syncthreads();
    }
    const int crow0 = (lane >> 4) << 2, ccol = lane & 15;
#pragma unroll
    for (int n = 0; n < 4; ++n) {
        const int col = bn0 + wc + n * 16 + ccol;
        const float bv = bias[col];
#pragma unroll
        for (int m = 0; m < 4; ++m) {
            const int row = bm0 + wr + m * 16 + crow0;
#pragma unroll
            for (int j = 0; j < 4; ++j)
                out[(size_t)(row + j) * N_DIM + col] = acc[m][n][j] + bv;
        }
    }
}

extern "C" void kernel_launch(void* const* d_in, const int* in_sizes, int n_in,
                              void* d_out, int out_size, void* d_ws, size_t ws_size,
                              hipStream_t stream)
{
    const float* x   = (const float*)d_in[0];
    const int*   qw  = (const int*)d_in[1];
    const int*   qz  = (const int*)d_in[2];
    const float* scl = (const float*)d_in[3];
    const float* bs  = (const float*)d_in[4];
    float* out = (float*)d_out;

    const int M = in_sizes[0] / K_DIM;               // 4096
    const size_t xh_bytes = (size_t)M * K_DIM * 2;   // 33.6 MB

    if (ws_size >= xh_bytes) {
        __half* xh = (__half*)d_ws;
        const int nchunks = M * K_DIM / 8;
        hipLaunchKernelGGL(r13_xcvt, dim3(2048), dim3(256), 0, stream, x, xh, nchunks);
        dim3 grid((M / BM) * NT_N);                  // 16*43 = 688
        hipLaunchKernelGGL(r13_gemm, grid, dim3(512), 0, stream,
                           xh, qw, qz, scl, bs, out);
    } else {
        dim3 grid((M / 128) * 86);                   // 2752
        hipLaunchKernelGGL(r13_fb, grid, dim3(256), 0, stream,
                           x, qw, qz, scl, bs, out);
    }
}

// Round 15
// 386.235 us; speedup vs baseline: 1.0925x; 1.0030x over previous
//
#include <hip/hip_runtime.h>
#include <hip/hip_fp16.h>

#define K_DIM 4096
#define N_DIM 11008
#define NZ8   1376          // N_DIM/8
#define BM    256
#define BN    256
#define NT_N  43            // N_DIM/BN
#define NKT   64            // K_DIM/64
#define ATB   32768         // A tile bytes = 256*64*2

typedef _Float16 f16x8 __attribute__((ext_vector_type(8)));
typedef float    f32x4 __attribute__((ext_vector_type(4)));

#define SB()    __builtin_amdgcn_sched_barrier(0)
#define BAR()   __builtin_amdgcn_s_barrier()
#define VMW(N)  do { asm volatile("s_waitcnt vmcnt(" #N ")" ::: "memory"); SB(); } while (0)
#define LGKM0() do { asm volatile("s_waitcnt lgkmcnt(0)" ::: "memory"); SB(); } while (0)

// 1 int32 -> 8 fp16 dequant, (k,k+4)-interleaved order
__device__ __forceinline__ f16x8 dq8(unsigned q, __half2 scp, __half2 nzp)
{
    const unsigned mu = 0xE400E400u;
    const __half2 m1024 = *(const __half2*)&mu;
    union { __half2 h2[4]; f16x8 v; } p;
#pragma unroll
    for (int d = 0; d < 4; ++d) {
        unsigned t = ((q >> (4 * d)) & 0x000F000Fu) | 0x64006400u;
        p.h2[d] = __hfma2(__hadd2(*(const __half2*)&t, m1024), scp, nzp);
    }
    return p.v;
}

// ---- pre-pass: x f32 -> fp16 ws, layout [mtile][ktile][kh][slot][row][16B]
// (identical to r13/r14; GEMM A-stage = linear global_load_lds, conflict-free)
__global__ __launch_bounds__(256)
void r15_xcvt(const float* __restrict__ x, __half* __restrict__ xh, int nchunks)
{
    int c = blockIdx.x * 256 + threadIdx.x;
    const int stride = gridDim.x * 256;
    for (; c < nchunks; c += stride) {
        const int row = c & 255;
        const int sl  = (c >> 8) & 3;
        const int kh  = (c >> 10) & 1;
        const int tl  = c >> 11;
        const int mt  = tl >> 6;
        const int kt  = tl & 63;
        const size_t gm = (size_t)mt * 256 + row;
        const int kb = kt * 64 + kh * 32 + sl * 8;
        const float4 f0 = *(const float4*)(x + gm * K_DIM + kb);
        const float4 f1 = *(const float4*)(x + gm * K_DIM + kb + 4);
        union { __half2 h2[4]; int4 v; } p;
        p.h2[0] = __floats2half2_rn(f0.x, f1.x);
        p.h2[1] = __floats2half2_rn(f0.y, f1.y);
        p.h2[2] = __floats2half2_rn(f0.z, f1.z);
        p.h2[3] = __floats2half2_rn(f0.w, f1.w);
        ((int4*)xh)[c] = p.v;
    }
}

// ---- ledger issue helpers (all loads = r13's proven 64-bit-vaddr asm form) --
// 8 q-dwords for one tile: rows kt*8+kb8 / kt*8+kb8+4, cols ngl2+{0,16,32,48}
#define ISSUE_Q8(D0,D1,D2,D3,D4,D5,D6,D7) do { \
    asm volatile( \
        "global_load_dword %0, %8, off\n\t" \
        "global_load_dword %1, %8, off offset:64\n\t" \
        "global_load_dword %2, %8, off offset:128\n\t" \
        "global_load_dword %3, %8, off offset:192\n\t" \
        "global_load_dword %4, %9, off\n\t" \
        "global_load_dword %5, %9, off offset:64\n\t" \
        "global_load_dword %6, %9, off offset:128\n\t" \
        "global_load_dword %7, %9, off offset:192" \
        : "=&v"(D0), "=&v"(D1), "=&v"(D2), "=&v"(D3), \
          "=&v"(D4), "=&v"(D5), "=&v"(D6), "=&v"(D7) \
        : "v"(qp0), "v"(qp1) : "memory"); \
    qp0 += 8 * N_DIM; qp1 += 8 * N_DIM; \
} while (0)

// 4 scales + 4 qzero dwords for the NEXT group (cols ngl2+{0,16,32,48})
#define ISSUE_SZ() do { \
    asm volatile( \
        "global_load_dword %0, %8, off\n\t" \
        "global_load_dword %1, %8, off offset:64\n\t" \
        "global_load_dword %2, %8, off offset:128\n\t" \
        "global_load_dword %3, %8, off offset:192\n\t" \
        "global_load_dword %4, %9, off\n\t" \
        "global_load_dword %5, %9, off offset:8\n\t" \
        "global_load_dword %6, %9, off offset:16\n\t" \
        "global_load_dword %7, %9, off offset:24" \
        : "=&v"(sS0), "=&v"(sS1), "=&v"(sS2), "=&v"(sS3), \
          "=&v"(sZ0), "=&v"(sZ1), "=&v"(sZ2), "=&v"(sZ3) \
        : "v"(sp), "v"(zp) : "memory"); \
    sp += N_DIM; zp += NZ8; \
} while (0)

#define ISSUE_A(BUFP, T) do { \
    const char* _s = agp + (size_t)(T) * ATB; \
    _Pragma("unroll") for (int j = 0; j < 4; ++j) \
        __builtin_amdgcn_global_load_lds((const unsigned int*)(_s + j * 8192), \
            (unsigned int*)((BUFP) + j * 8192 + tid * 16), 16, 0, 0); \
} while (0)

#define FRAGS(ARp, KH) do { \
    _Pragma("unroll") for (int m = 0; m < 8; ++m) \
        af[m] = *(const f16x8*)((ARp) + (KH) * 16384 + aOff + m * 256); \
} while (0)

#define DQ4(Q0,Q1,Q2,Q3) do { \
    bf[0] = dq8(Q0, scp0, nzp0); bf[1] = dq8(Q1, scp1, nzp1); \
    bf[2] = dq8(Q2, scp2, nzp2); bf[3] = dq8(Q3, scp3, nzp3); \
} while (0)

#define MFMA32() do { \
    __builtin_amdgcn_s_setprio(1); \
    _Pragma("unroll") for (int m = 0; m < 8; ++m) \
        _Pragma("unroll") for (int n = 0; n < 4; ++n) \
            acc[m][n] = __builtin_amdgcn_mfma_f32_16x16x32_f16(af[m], bf[n], acc[m][n], 0, 0, 0); \
    __builtin_amdgcn_s_setprio(0); \
    SB(); \
} while (0)

#define CVT_S() do { \
    const float _s0 = __uint_as_float(sS0), _s1 = __uint_as_float(sS1); \
    const float _s2 = __uint_as_float(sS2), _s3 = __uint_as_float(sS3); \
    const __half _h0 = __float2half_rn(_s0), _h1 = __float2half_rn(_s1); \
    const __half _h2 = __float2half_rn(_s2), _h3 = __float2half_rn(_s3); \
    scp0 = __half2(_h0, _h0); scp1 = __half2(_h1, _h1); \
    scp2 = __half2(_h2, _h2); scp3 = __half2(_h3, _h3); \
    const __half _n0 = __float2half_rn(-_s0 * (float)((sZ0 >> sh4) & 15u)); \
    const __half _n1 = __float2half_rn(-_s1 * (float)((sZ1 >> sh4) & 15u)); \
    const __half _n2 = __float2half_rn(-_s2 * (float)((sZ2 >> sh4) & 15u)); \
    const __half _n3 = __float2half_rn(-_s3 * (float)((sZ3 >> sh4) & 15u)); \
    nzp0 = __half2(_n0, _n0); nzp1 = __half2(_n1, _n1); \
    nzp2 = __half2(_n2, _n2); nzp3 = __half2(_n3, _n3); \
} while (0)

// ---- fused GEMM: 256x256, 8 waves (2Mx4N), B dequant-to-register (no B LDS).
// LDS = 2x32KB A dbuf. One barrier per k-tile. Counted-vmcnt ledger:
// q/scales 2 tiles ahead, A-DMA 1 tile ahead; vmcnt never 0 in steady state.
__global__ __launch_bounds__(512, 2)
void r15_gemm(const __half* __restrict__ xh,
              const int*   __restrict__ qweight,
              const int*   __restrict__ qzeros,
              const float* __restrict__ scales,
              const float* __restrict__ bias,
              float* __restrict__ out)
{
    __shared__ __align__(16) unsigned char A0s[ATB], A1s[ATB];   // 64 KB

    const int tid  = threadIdx.x;
    const int lane = tid & 63;
    const int wid  = tid >> 6;
    const int wr   = (wid >> 2) * 128;   // wave M offset (0,128)
    const int wc   = (wid & 3) * 64;     // wave N offset (0,64,128,192)

    int bid = blockIdx.x;                // XCD swizzle (688 = 8*86)
    const int cpx = gridDim.x >> 3;
    bid = (bid & 7) * cpx + (bid >> 3);
    const int bm0 = (bid / NT_N) * BM;
    const int bn0 = (bid % NT_N) * BN;

    const int frow = lane & 15, kb8 = lane >> 4;
    const int ngl2 = bn0 + wc + frow;            // this lane's base column
    const int sh4  = (ngl2 & 7) * 4;
    const int aOff = kb8 * 4096 + (wr + frow) * 16;

    const char* agp = (const char*)xh + ((size_t)(bm0 >> 8) * NKT) * ATB + tid * 16;

    // running pointers (64-bit vaddr form, r13-proven)
    const int*   qp0 = qweight + (size_t)kb8 * N_DIM + ngl2;          // kh0 rows
    const int*   qp1 = qweight + (size_t)(kb8 + 4) * N_DIM + ngl2;    // kh1 rows
    const float* sp  = scales + (size_t)N_DIM + ngl2;                 // group 1
    const int*   zp  = qzeros + (size_t)NZ8 + (ngl2 >> 3);            // group 1

    unsigned char *aR = A0s, *aW = A1s;

    f32x4 acc[8][4];
#pragma unroll
    for (int m = 0; m < 8; ++m)
#pragma unroll
        for (int n = 0; n < 4; ++n)
            acc[m][n] = (f32x4){0.f, 0.f, 0.f, 0.f};
    f16x8 af[8], bf[4];
    __half2 scp0, scp1, scp2, scp3, nzp0, nzp1, nzp2, nzp3;
    unsigned qa0, qa1, qa2, qa3, qa4, qa5, qa6, qa7;
    unsigned qb0, qb1, qb2, qb3, qb4, qb5, qb6, qb7;
    unsigned sS0, sS1, sS2, sS3, sZ0, sZ1, sZ2, sZ3;

    // ---- prologue: group-0 scales plain-loaded & retired before the ledger
    sS0 = __float_as_uint(scales[ngl2]);
    sS1 = __float_as_uint(scales[ngl2 + 16]);
    sS2 = __float_as_uint(scales[ngl2 + 32]);
    sS3 = __float_as_uint(scales[ngl2 + 48]);
    sZ0 = (unsigned)qzeros[(ngl2 >> 3) + 0];
    sZ1 = (unsigned)qzeros[(ngl2 >> 3) + 2];
    sZ2 = (unsigned)qzeros[(ngl2 >> 3) + 4];
    sZ3 = (unsigned)qzeros[(ngl2 >> 3) + 6];
    asm volatile("" : "+v"(sS0), "+v"(sS1), "+v"(sS2), "+v"(sS3),
                      "+v"(sZ0), "+v"(sZ1), "+v"(sZ2), "+v"(sZ3));
    VMW(0);
    // ledger: qa(t0)[8], A(0)[4], qb(t1)[8], A(1)[4]  -> 24 outstanding
    ISSUE_Q8(qa0, qa1, qa2, qa3, qa4, qa5, qa6, qa7);   // tile 0
    ISSUE_A(aR, 0);
    ISSUE_Q8(qb0, qb1, qb2, qb3, qb4, qb5, qb6, qb7);   // tile 1
    ISSUE_A(aW, 1);
    VMW(12);                     // retire qa[8]+A(0)[4]; leaves qb[8]+A(1)[4]
    BAR();

    // ---- main loop: u = 0..30, tiles (2u, 2u+1); issues for 2u+2, 2u+3
    for (int u = 0; u < 31; ++u) {
        const int t0 = 2 * u;
        CVT_S();                                 // group u (raw retired)
        // ===== even tile t0 =====
        FRAGS(aR, 0); DQ4(qa0, qa1, qa2, qa3); LGKM0(); MFMA32();
        FRAGS(aR, 1); DQ4(qa4, qa5, qa6, qa7);
        ISSUE_Q8(qa0, qa1, qa2, qa3, qa4, qa5, qa6, qa7);   // tile t0+2
        ISSUE_SZ();                                          // group u+1
        LGKM0(); MFMA32();
        VMW(16);                 // retire qb(t0+1)[8]+A(t0+1)[4]; leaves qa+S
        BAR(); SB();
        { unsigned char* tp = aR; aR = aW; aW = tp; }
        ISSUE_A(aW, t0 + 2);
        // ===== odd tile t0+1 =====
        FRAGS(aR, 0); DQ4(qb0, qb1, qb2, qb3); LGKM0(); MFMA32();
        FRAGS(aR, 1); DQ4(qb4, qb5, qb6, qb7);
        ISSUE_Q8(qb0, qb1, qb2, qb3, qb4, qb5, qb6, qb7);   // tile t0+3
        LGKM0(); MFMA32();
        VMW(8);                  // retire qa(t0+2)[8]+S[8]+A(t0+2)[4]; leaves qb
        BAR(); SB();
        { unsigned char* tp = aR; aR = aW; aW = tp; }
        ISSUE_A(aW, t0 + 3);
    }

    // ---- tail: tiles 62, 63 (group 31 retired; qb(63)[8]+A(63)[4] in flight)
    CVT_S();
    FRAGS(aR, 0); DQ4(qa0, qa1, qa2, qa3); LGKM0(); MFMA32();
    FRAGS(aR, 1); DQ4(qa4, qa5, qa6, qa7); LGKM0(); MFMA32();
    VMW(0);                      // drain qb(63) + A(63)
    BAR(); SB();
    { unsigned char* tp = aR; aR = aW; aW = tp; }
    FRAGS(aR, 0); DQ4(qb0, qb1, qb2, qb3); LGKM0(); MFMA32();
    FRAGS(aR, 1); DQ4(qb4, qb5, qb6, qb7); LGKM0(); MFMA32();

    // ---- epilogue: C row=(lane>>4)*4+j, col=lane&15 (m89 layout)
    const int crow0 = (lane >> 4) << 2, ccol = lane & 15;
#pragma unroll
    for (int n = 0; n < 4; ++n) {
        const int col = bn0 + wc + n * 16 + ccol;
        const float bv = bias[col];
#pragma unroll
        for (int m = 0; m < 8; ++m) {
            const int row = bm0 + wr + m * 16 + crow0;
#pragma unroll
            for (int j = 0; j < 4; ++j)
                out[(size_t)(row + j) * N_DIM + col] = acc[m][n][j] + bv;
        }
    }
}

// ---------------- fallback (ws too small): proven r8 kernel ----------------
typedef __bf16 bf16x8 __attribute__((ext_vector_type(8)));

__global__ __launch_bounds__(256, 2)
void r15_fb(const float* __restrict__ x,
            const int*   __restrict__ qweight,
            const int*   __restrict__ qzeros,
            const float* __restrict__ scales,
            const float* __restrict__ bias,
            float* __restrict__ out)
{
    __shared__ __align__(16) unsigned char Asm[128 * 64 * 2];
    __shared__ __align__(16) unsigned char Bsm[128 * 64 * 2];
    const int tid = threadIdx.x, lane = tid & 63, wv = tid >> 6;
    const int wr = (wv >> 1) * 64, wc = (wv & 1) * 64;
    int bid = blockIdx.x;
    const int cpx = gridDim.x >> 3;
    bid = (bid & 7) * cpx + (bid >> 3);
    const int bm0 = (bid / 86) * 128, bn0 = (bid % 86) * 128;
    const int ar = tid >> 4, ac4 = tid & 15;
    const float* xp = x + (size_t)(bm0 + ar) * K_DIM + ac4 * 4;
    unsigned char* aw = Asm + ar * 128 + ((ac4 * 8) ^ ((ar & 7) << 4));
    const int bnn = tid & 127, bk8q = tid >> 7, ngl = bn0 + bnn;
    const int* qwp = qweight + (size_t)bk8q * N_DIM + ngl;
    unsigned char* bw = Bsm + bnn * 128;
    const int bsw = bnn & 7;
    const int frow = lane & 15, kb8 = lane >> 4, fsw = frow & 7;
    f32x4 acc[4][4];
#pragma unroll
    for (int m = 0; m < 4; ++m)
#pragma unroll
        for (int n = 0; n < 4; ++n) acc[m][n] = (f32x4){0.f, 0.f, 0.f, 0.f};
    float sc = 0.f, nsz = 0.f;
    for (int kt = 0; kt < K_DIM / 64; ++kt) {
        const int k0 = kt * 64;
        if ((k0 & 127) == 0) {
            const int g = k0 >> 7;
            sc = scales[(size_t)g * N_DIM + ngl];
            const unsigned zq = (unsigned)qzeros[(size_t)g * NZ8 + (ngl >> 3)];
            nsz = -sc * (float)((zq >> ((ngl & 7) * 4)) & 15u);
        }
#pragma unroll
        for (int i = 0; i < 8; ++i) {
            const float4 v = *(const float4*)(xp + (size_t)i * 16 * K_DIM + k0);
            union { __bf16 h[4]; unsigned long long u; } p;
            p.h[0] = (__bf16)v.x; p.h[1] = (__bf16)v.y;
            p.h[2] = (__bf16)v.z; p.h[3] = (__bf16)v.w;
            *(unsigned long long*)(aw + i * 16 * 128) = p.u;
        }
#pragma unroll
        for (int i = 0; i < 4; ++i) {
            const int k8 = 2 * i + bk8q;
            const unsigned q = (unsigned)qwp[(size_t)(kt * 8 + 2 * i) * N_DIM];
            union { __bf16 h[8]; bf16x8 v8; } p;
#pragma unroll
            for (int j = 0; j < 8; ++j)
                p.h[j] = (__bf16)__builtin_fmaf(sc, (float)((q >> (4 * j)) & 15u), nsz);
            *(bf16x8*)(bw + ((k8 ^ bsw) << 4)) = p.v8;
        }
        __syncthreads();
#pragma unroll
        for (int kh = 0; kh < 2; ++kh) {
            const int ksl = (kh << 2) + kb8;
            bf16x8 a2[4], b2[4];
#pragma unroll
            for (int m = 0; m < 4; ++m)
                a2[m] = *(const bf16x8*)(Asm + (wr + m * 16 + frow) * 128 + ((ksl ^ fsw) << 4));
#pragma unroll
            for (int n = 0; n < 4; ++n)
                b2[n] = *(const bf16x8*)(Bsm + (wc + n * 16 + frow) * 128 + ((ksl ^ fsw) << 4));
#pragma unroll
            for (int m = 0; m < 4; ++m)
#pragma unroll
                for (int n = 0; n < 4; ++n)
                    acc[m][n] = __builtin_amdgcn_mfma_f32_16x16x32_bf16(a2[m], b2[n], acc[m][n], 0, 0, 0);
        }
        __syncthreads();
    }
    const int crow0 = (lane >> 4) << 2, ccol = lane & 15;
#pragma unroll
    for (int n = 0; n < 4; ++n) {
        const int col = bn0 + wc + n * 16 + ccol;
        const float bv = bias[col];
#pragma unroll
        for (int m = 0; m < 4; ++m) {
            const int row = bm0 + wr + m * 16 + crow0;
#pragma unroll
            for (int j = 0; j < 4; ++j)
                out[(size_t)(row + j) * N_DIM + col] = acc[m][n][j] + bv;
        }
    }
}

extern "C" void kernel_launch(void* const* d_in, const int* in_sizes, int n_in,
                              void* d_out, int out_size, void* d_ws, size_t ws_size,
                              hipStream_t stream)
{
    const float* x   = (const float*)d_in[0];
    const int*   qw  = (const int*)d_in[1];
    const int*   qz  = (const int*)d_in[2];
    const float* scl = (const float*)d_in[3];
    const float* bs  = (const float*)d_in[4];
    float* out = (float*)d_out;

    const int M = in_sizes[0] / K_DIM;               // 4096
    const size_t xh_bytes = (size_t)M * K_DIM * 2;   // 33.6 MB

    if (ws_size >= xh_bytes) {
        __half* xh = (__half*)d_ws;
        const int nchunks = M * K_DIM / 8;
        hipLaunchKernelGGL(r15_xcvt, dim3(2048), dim3(256), 0, stream, x, xh, nchunks);
        dim3 grid((M / BM) * NT_N);                  // 688
        hipLaunchKernelGGL(r15_gemm, grid, dim3(512), 0, stream,
                           xh, qw, qz, scl, bs, out);
    } else {
        dim3 grid((M / 128) * 86);                   // 2752
        hipLaunchKernelGGL(r15_fb, grid, dim3(256), 0, stream,
                           x, qw, qz, scl, bs, out);
    }
}